// Round 12
// baseline (390.009 us; speedup 1.0000x reference)
//
#include <hip/hip_runtime.h>
#include <hip/hip_bf16.h>

#define IN_F  8192
#define OUT_F 8192
#define BATCH 16
#define KSPLIT 16
#define KCHUNK (IN_F / KSPLIT)     // 512 k per block
#define NSTEPS (KCHUNK / 32)       // 16 mfma k-steps
#define THREADS 256                // 4 waves
#define ROWS_PER_BLOCK 64          // 4 waves x 16 rows
#define NROWGRP (OUT_F / ROWS_PER_BLOCK)                 // 128
#define XPAD 8
#define XSTRIDE (KCHUNK + XPAD)    // 520 shorts
#define CNT_OFF ((size_t)KSPLIT * BATCH * OUT_F)         // float index of counters
#define WS_NEEDED (CNT_OFF * 4 + NROWGRP * 4)            // 8 MB + 512 B

typedef __attribute__((ext_vector_type(8))) short bf16x8;
typedef __attribute__((ext_vector_type(4))) float f32x4;

// ---------- fallback path: bias-init + atomics ----------
__global__ __launch_bounds__(256)
void init_out_kernel(const float* __restrict__ bias, float* __restrict__ out)
{
    const int i = blockIdx.x * 256 + threadIdx.x;
    out[i] = bias[i & (OUT_F - 1)];
}

template<bool USE_WS>
__global__ __launch_bounds__(THREADS, 8)   // cap 64 VGPR -> 8 blocks/CU
void gptq_mfma_kernel(const float* __restrict__ x,
                      const int*  __restrict__ qw,
                      const float* __restrict__ scale,
                      const float* __restrict__ bias,
                      float* __restrict__ ws,    // partials + counters (USE_WS)
                      int*   __restrict__ cnt,
                      float* __restrict__ out)
{
    __shared__ __align__(16) unsigned short xs[BATCH][XSTRIDE];   // 16.6 KB
    __shared__ int is_last;

    const int tid  = threadIdx.x;
    const int lane = tid & 63;
    const int wave = tid >> 6;
    const int mn   = lane & 15;        // A: batch m    B: out-row n
    const int kgrp = lane >> 4;        // k-group 0..3
    const int kidx = blockIdx.x & (KSPLIT - 1);
    const int rowgrp = blockIdx.x >> 4;
    const int row0 = rowgrp * ROWS_PER_BLOCK + wave * 16;
    const int k0   = kidx * KCHUNK;

    // per-block k-phase stagger (R11): spreads HBM channel phases
    const int s0 = rowgrp & (NSTEPS - 1);

    const int* qsrc = qw + (size_t)(row0 + mn) * IN_F + k0 + kgrp * 8;

    // ---- prologue weight loads FIRST (independent of LDS): overlap the stage ----
    int4 ca = *reinterpret_cast<const int4*>(qsrc + s0 * 32);
    int4 cb = *reinterpret_cast<const int4*>(qsrc + s0 * 32 + 4);

    // ---- stage x panel once (bf16): row = 512 f32 = 256 threads x float2 ----
    #pragma unroll
    for (int r = 0; r < BATCH; ++r) {
        const float2 v = *reinterpret_cast<const float2*>(x + (size_t)r * IN_F + k0 + tid * 2);
        unsigned int p = (__bfloat16_as_ushort(__float2bfloat16(v.y)) << 16)
                       |  __bfloat16_as_ushort(__float2bfloat16(v.x));
        *reinterpret_cast<unsigned int*>(&xs[r][tid * 2]) = p;
    }
    __syncthreads();

    const unsigned short* asrc = &xs[mn][kgrp * 8];
    bf16x8 ac = *reinterpret_cast<const bf16x8*>(asrc + s0 * 32);

    f32x4 acc = {0.f, 0.f, 0.f, 0.f};

    int sidx = s0;
    #pragma unroll 1   // 1-deep pipeline; bounded registers (<=64)
    for (int t = 0; t < NSTEPS; ++t) {
        int4 na, nb;
        bf16x8 an;
        const bool more = (t + 1 < NSTEPS);
        const int snext = (sidx + 1) & (NSTEPS - 1);
        if (more) {
            na = *reinterpret_cast<const int4*>(qsrc + snext * 32);
            nb = *reinterpret_cast<const int4*>(qsrc + snext * 32 + 4);
            an = *reinterpret_cast<const bf16x8*>(asrc + snext * 32);
        }

        bf16x8 bw;   // int4-valued weights (-8..7) are exact in bf16
        bw[0] = __bfloat16_as_short(__float2bfloat16((float)ca.x));
        bw[1] = __bfloat16_as_short(__float2bfloat16((float)ca.y));
        bw[2] = __bfloat16_as_short(__float2bfloat16((float)ca.z));
        bw[3] = __bfloat16_as_short(__float2bfloat16((float)ca.w));
        bw[4] = __bfloat16_as_short(__float2bfloat16((float)cb.x));
        bw[5] = __bfloat16_as_short(__float2bfloat16((float)cb.y));
        bw[6] = __bfloat16_as_short(__float2bfloat16((float)cb.z));
        bw[7] = __bfloat16_as_short(__float2bfloat16((float)cb.w));

        acc = __builtin_amdgcn_mfma_f32_16x16x32_bf16(ac, bw, acc, 0, 0, 0);

        if (more) { ca = na; cb = nb; ac = an; }
        sidx = snext;
    }

    // C mapping (m89/R5/R8-verified): col = mn = n, row = kgrp*4 + v = batch m
    const float sc = scale[0];

    if (!USE_WS) {
        #pragma unroll
        for (int v = 0; v < 4; ++v) {
            const int m = kgrp * 4 + v;
            atomicAdd(out + (size_t)m * OUT_F + row0 + mn, acc[v] * sc);
        }
        return;
    }

    // ---- partials (non-temporal: don't evict qweight from L3) ----
    #pragma unroll
    for (int v = 0; v < 4; ++v) {
        const int m = kgrp * 4 + v;
        __builtin_nontemporal_store(
            acc[v], ws + (size_t)kidx * BATCH * OUT_F + (size_t)m * OUT_F + row0 + mn);
    }

    // ---- last block of this rowgrp reduces (overlaps other blocks' streaming) ----
    __threadfence();                 // release: partials device-visible
    __syncthreads();                 // all threads of block fenced
    if (tid == 0)
        is_last = (atomicAdd(cnt + rowgrp, 1) == KSPLIT - 1);
    __syncthreads();

    if (is_last) {
        __threadfence();             // acquire: see all blocks' partials
        const int m    = tid >> 4;                        // 0..15 batch
        const int gcol = rowgrp * ROWS_PER_BLOCK + (tid & 15) * 4;
        f32x4 s = {0.f, 0.f, 0.f, 0.f};
        #pragma unroll
        for (int k = 0; k < KSPLIT; ++k) {
            const f32x4 p = __builtin_nontemporal_load(
                reinterpret_cast<const f32x4*>(ws + (size_t)k * BATCH * OUT_F + (size_t)m * OUT_F + gcol));
            s += p;
        }
        const float4 bv = *reinterpret_cast<const float4*>(bias + gcol);
        float4 r;
        r.x = s[0] * sc + bv.x; r.y = s[1] * sc + bv.y;
        r.z = s[2] * sc + bv.z; r.w = s[3] * sc + bv.w;
        *reinterpret_cast<float4*>(out + (size_t)m * OUT_F + gcol) = r;
    }
}

extern "C" void kernel_launch(void* const* d_in, const int* in_sizes, int n_in,
                              void* d_out, int out_size, void* d_ws, size_t ws_size,
                              hipStream_t stream) {
    const float* x     = (const float*)d_in[0];
    const int*   qw    = (const int*)d_in[1];
    const float* scale = (const float*)d_in[2];
    const float* bias  = (const float*)d_in[3];
    float*       out   = (float*)d_out;
    float*       ws    = (float*)d_ws;
    int*         cnt   = (int*)(ws + CNT_OFF);

    dim3 grid(NROWGRP * KSPLIT);   // 128 x 16 = 2048 blocks = 8/CU

    if (ws_size >= WS_NEEDED) {
        hipMemsetAsync(cnt, 0, NROWGRP * sizeof(int), stream);   // graph-legal memset node
        gptq_mfma_kernel<true><<<grid, THREADS, 0, stream>>>(x, qw, scale, bias, ws, cnt, out);
    } else {
        init_out_kernel<<<(BATCH * OUT_F) / 256, 256, 0, stream>>>(bias, out);
        gptq_mfma_kernel<false><<<grid, THREADS, 0, stream>>>(x, qw, scale, bias, ws, cnt, out);
    }
}

// Round 13
// 51.907 us; speedup vs baseline: 7.5136x; 7.5136x over previous
//
#include <hip/hip_runtime.h>
#include <hip/hip_bf16.h>

#define IN_F  8192
#define OUT_F 8192
#define BATCH 16
#define KSPLIT 16
#define KCHUNK (IN_F / KSPLIT)     // 512 k per block
#define NSTEPS (KCHUNK / 32)       // 16 mfma k-steps
#define THREADS 512                // 8 waves
#define ROWS_PER_BLOCK 128         // 8 waves x 16 rows
#define NROWGRP (OUT_F / ROWS_PER_BLOCK)                 // 64
#define XPAD 8
#define XSTRIDE (KCHUNK + XPAD)    // 520 shorts
#define WS_NEEDED ((size_t)KSPLIT * BATCH * OUT_F * 4)   // 8 MB

typedef __attribute__((ext_vector_type(8))) short bf16x8;
typedef __attribute__((ext_vector_type(4))) float f32x4;

// ---------- fallback path: bias-init + atomics ----------
__global__ __launch_bounds__(256)
void init_out_kernel(const float* __restrict__ bias, float* __restrict__ out)
{
    const int i = blockIdx.x * 256 + threadIdx.x;
    out[i] = bias[i & (OUT_F - 1)];
}

// ---------- reduce: out[b][o] = scale * sum_k ws[k][b][o] + bias[o] ----------
__global__ __launch_bounds__(256)
void reduce_kernel(const float* __restrict__ ws,
                   const float* __restrict__ scale,
                   const float* __restrict__ bias,
                   float* __restrict__ out)
{
    const int idx = (blockIdx.x * 256 + threadIdx.x) * 4;   // over BATCH*OUT_F
    const int o   = idx & (OUT_F - 1);
    float4 s = {0.f, 0.f, 0.f, 0.f};
    #pragma unroll
    for (int k = 0; k < KSPLIT; ++k) {
        const float4 p = *reinterpret_cast<const float4*>(ws + (size_t)k * BATCH * OUT_F + idx);
        s.x += p.x; s.y += p.y; s.z += p.z; s.w += p.w;
    }
    const float sc = scale[0];
    const float4 bv = *reinterpret_cast<const float4*>(bias + o);
    float4 r;
    r.x = s.x * sc + bv.x; r.y = s.y * sc + bv.y;
    r.z = s.z * sc + bv.z; r.w = s.w * sc + bv.w;
    *reinterpret_cast<float4*>(out + idx) = r;
}

template<bool USE_WS>
__global__ __launch_bounds__(THREADS, 8)   // 8 waves/EU -> 64 VGPR cap, 4 blocks/CU
void gptq_mfma_kernel(const float* __restrict__ x,
                      const int*  __restrict__ qw,
                      const float* __restrict__ scale,
                      float* __restrict__ dst)
{
    __shared__ __align__(16) unsigned short xs[BATCH][XSTRIDE];   // 16.6 KB

    const int tid  = threadIdx.x;
    const int lane = tid & 63;
    const int wave = tid >> 6;
    const int mn   = lane & 15;        // A: batch m    B: out-row n
    const int kgrp = lane >> 4;        // k-group 0..3
    const int kidx = blockIdx.x & (KSPLIT - 1);
    const int rowgrp = blockIdx.x >> 4;
    const int row0 = rowgrp * ROWS_PER_BLOCK;
    const int wrow = row0 + wave * 16 + mn;     // this lane's weight row
    const int k0   = kidx * KCHUNK;

    // per-block k-phase stagger (R11): spreads HBM channel phases
    const int s0 = rowgrp & (NSTEPS - 1);

    const int* qsrc = qw + (size_t)wrow * IN_F + k0 + kgrp * 8;

    // ---- prologue weight loads FIRST (independent of LDS): overlap the stage ----
    int4 ca = *reinterpret_cast<const int4*>(qsrc + s0 * 32);
    int4 cb = *reinterpret_cast<const int4*>(qsrc + s0 * 32 + 4);

    // ---- stage x panel once (bf16): 2048 float4s, 512 threads x 4 ----
    #pragma unroll
    for (int j = 0; j < 4; ++j) {
        const int fidx = j * THREADS + tid;     // float4 index over the panel
        const int r    = fidx >> 7;             // 128 float4 per row
        const int c    = (fidx & 127) * 4;
        const float4 v = *reinterpret_cast<const float4*>(x + (size_t)r * IN_F + k0 + c);
        ushort4 p;
        p.x = __bfloat16_as_ushort(__float2bfloat16(v.x));
        p.y = __bfloat16_as_ushort(__float2bfloat16(v.y));
        p.z = __bfloat16_as_ushort(__float2bfloat16(v.z));
        p.w = __bfloat16_as_ushort(__float2bfloat16(v.w));
        *reinterpret_cast<ushort4*>(&xs[r][c]) = p;
    }
    __syncthreads();   // the ONLY barrier

    const unsigned short* asrc = &xs[mn][kgrp * 8];
    bf16x8 ac = *reinterpret_cast<const bf16x8*>(asrc + s0 * 32);

    f32x4 acc = {0.f, 0.f, 0.f, 0.f};

    int sidx = s0;
    #pragma unroll 1   // 1-deep pipeline; bounded registers (<=64)
    for (int t = 0; t < NSTEPS; ++t) {
        int4 na, nb;
        bf16x8 an;
        const bool more = (t + 1 < NSTEPS);
        const int snext = (sidx + 1) & (NSTEPS - 1);
        if (more) {
            na = *reinterpret_cast<const int4*>(qsrc + snext * 32);
            nb = *reinterpret_cast<const int4*>(qsrc + snext * 32 + 4);
            an = *reinterpret_cast<const bf16x8*>(asrc + snext * 32);
        }

        bf16x8 bw;   // int4-valued weights (-8..7) are exact in bf16
        bw[0] = __bfloat16_as_short(__float2bfloat16((float)ca.x));
        bw[1] = __bfloat16_as_short(__float2bfloat16((float)ca.y));
        bw[2] = __bfloat16_as_short(__float2bfloat16((float)ca.z));
        bw[3] = __bfloat16_as_short(__float2bfloat16((float)ca.w));
        bw[4] = __bfloat16_as_short(__float2bfloat16((float)cb.x));
        bw[5] = __bfloat16_as_short(__float2bfloat16((float)cb.y));
        bw[6] = __bfloat16_as_short(__float2bfloat16((float)cb.z));
        bw[7] = __bfloat16_as_short(__float2bfloat16((float)cb.w));

        acc = __builtin_amdgcn_mfma_f32_16x16x32_bf16(ac, bw, acc, 0, 0, 0);

        if (more) { ca = na; cb = nb; ac = an; }
        sidx = snext;
    }

    // C mapping (m89/R5/R8-verified): col = mn = n, row = kgrp*4 + v = batch m
    const float sc = scale[0];
    #pragma unroll
    for (int v = 0; v < 4; ++v) {
        const int m = kgrp * 4 + v;
        if (USE_WS) {
            dst[(size_t)kidx * BATCH * OUT_F + (size_t)m * OUT_F + wrow] = acc[v];
        } else {
            atomicAdd(dst + (size_t)m * OUT_F + wrow, acc[v] * sc);
        }
    }
}

extern "C" void kernel_launch(void* const* d_in, const int* in_sizes, int n_in,
                              void* d_out, int out_size, void* d_ws, size_t ws_size,
                              hipStream_t stream) {
    const float* x     = (const float*)d_in[0];
    const int*   qw    = (const int*)d_in[1];
    const float* scale = (const float*)d_in[2];
    const float* bias  = (const float*)d_in[3];
    float*       out   = (float*)d_out;
    float*       ws    = (float*)d_ws;

    dim3 grid(NROWGRP * KSPLIT);   // 64 x 16 = 1024 blocks = 4/CU

    if (ws_size >= WS_NEEDED) {
        gptq_mfma_kernel<true><<<grid, THREADS, 0, stream>>>(x, qw, scale, ws);
        reduce_kernel<<<(BATCH * OUT_F) / 4 / 256, 256, 0, stream>>>(ws, scale, bias, out);
    } else {
        init_out_kernel<<<(BATCH * OUT_F) / 256, 256, 0, stream>>>(bias, out);
        gptq_mfma_kernel<false><<<grid, THREADS, 0, stream>>>(x, qw, scale, out);
    }
}